// Round 6
// baseline (236.323 us; speedup 1.0000x reference)
//
#include <hip/hip_runtime.h>
#include <hip/hip_fp16.h>
#include <cstddef>

#define N_NODES 50000
#define E_EDGES 1600000
#define NEG_SLOPE 0.2f
#define LN_EPS 1e-5f
#define LOG2E 1.4426950408889634f
#define PAD 96        // max in-degree; Poisson(32) -> P(deg>96) ~ 1e-19

#define NBK 782       // dst buckets of 64 nodes: ceil(50000/64)
#define BCAP 2560     // entries per bucket (mean 2048, +11 sigma headroom)
#define PCH 4096      // edges per partition chunk
#define NCH 391       // ceil(E/PCH)
#define NGB 1563      // gemm blocks: ceil(N/32)
#define TPB 256

// ---------------- workspace layout (bytes) ----------------
// scal[0] = ew_sum, scal[4..7] = K[h]
#define OFF_SCAL    0u
#define OFF_BCUR    256u                       // NBK ints -> ends 3384
#define OFF_EWPART  4096u                      // NCH floats -> ends 5660
#define OFF_COUNTS  8192u                      // N ints -> 208,192
#define OFF_ASRC    208256u                    // N*4 floats -> 1,008,256
#define OFF_ADST    1008256u                   // N*4 floats -> 1,808,256
#define OFF_XPH     1808256u                   // N*128 halfs -> 14,608,256
#define OFF_PAIRS   14608256u                  // N*PAD uints -> 33,808,256
#define OFF_STAGE   33808256u                  // NBK*BCAP uint2 -> 49,823,616
#define OFF_WT      49823616u                  // 128x128 fp16 W^T -> 49,856,384

// LDS geometry for the MFMA gemm branch
#define XROW_B   272        // x-stage: 136 halves per row (128 + 8 pad); 32 rows = 8704 B
// sxp C-roundtrip: [32][132] fp32 = 16896 B (row stride 132 floats -> 2-way max on C-writes)

typedef _Float16 half8 __attribute__((ext_vector_type(8)));
typedef float f32x4_t __attribute__((ext_vector_type(4)));

__device__ __forceinline__ float lrelu(float x) { return x > 0.f ? x : NEG_SLOPE * x; }

__device__ __forceinline__ float sel4(float4 v, int h) {
    float ab = (h & 1) ? v.y : v.x;
    float cd = (h & 1) ? v.w : v.z;
    return (h & 2) ? cd : ab;
}

// prologue: W^T fp16 (once, global) + K[h] = sum_c W_edge[h,c]*att_edge[h,c]
__global__ __launch_bounds__(256) void k_w(const float* __restrict__ W,
                                           const float* __restrict__ W_edge,
                                           const float* __restrict__ att_edge,
                                           unsigned short* __restrict__ wt,
                                           float* __restrict__ scal) {
    int t = threadIdx.x;
    if (t < 128) {
        float p = W_edge[t] * att_edge[t];
        #pragma unroll
        for (int off = 16; off; off >>= 1) p += __shfl_down(p, off, 32);
        if ((t & 31) == 0) scal[4 + (t >> 5)] = p;
    }
    for (int i = t; i < 16384; i += 256) {
        int k = i >> 7, c = i & 127;
        wt[c * 128 + k] = __half_as_ushort(__float2half_rn(W[i]));
    }
}

// fused independent work: blocks [0,NCH) = edge partition (p1);
// blocks [NCH, NCH+NGB) = node GEMM (MFMA fp16, B-fragments direct from
// global WT -- no per-block W staging). bcur pre-zeroed via memset.
__global__ __launch_bounds__(256, 4) void k_A(const float* __restrict__ x,
                                              const unsigned short* __restrict__ wt,
                                              const float* __restrict__ att_src, const float* __restrict__ att_dst,
                                              const int* __restrict__ ei, const float* __restrict__ ew,
                                              unsigned short* __restrict__ xph, float* __restrict__ a_src,
                                              float* __restrict__ a_dst, float* __restrict__ scal,
                                              int* __restrict__ bcur, uint2* __restrict__ staging,
                                              float* __restrict__ ewPart) {
    __shared__ __align__(16) char smem[16896];
    int t = threadIdx.x;

    if (blockIdx.x < NCH) {
        // ---------------- p1: partition edges into 64-node dst buckets ------
        int* cnt   = (int*)smem;        // NBK ints
        int* gbase = cnt + NBK;         // NBK ints
        float* wred = (float*)(gbase + NBK);
        for (int i = t; i < NBK; i += 256) cnt[i] = 0;
        __syncthreads();

        int e0 = blockIdx.x * PCH;
        int lr[16];
        float s_ew = 0.f;
        #pragma unroll
        for (int i = 0; i < 16; i++) {
            int e = e0 + i * 256 + t;
            lr[i] = 0;
            if (e < E_EDGES) {
                int d = ei[E_EDGES + e];
                s_ew += ew[e];
                lr[i] = atomicAdd(&cnt[d >> 6], 1);
            }
        }
        #pragma unroll
        for (int off = 32; off; off >>= 1) s_ew += __shfl_down(s_ew, off, 64);
        if ((t & 63) == 0) wred[t >> 6] = s_ew;
        __syncthreads();
        if (t == 0) ewPart[blockIdx.x] = wred[0] + wred[1] + wred[2] + wred[3];
        for (int i = t; i < NBK; i += 256) gbase[i] = atomicAdd(&bcur[i], cnt[i]);
        __syncthreads();

        #pragma unroll
        for (int i = 0; i < 16; i++) {
            int e = e0 + i * 256 + t;
            if (e < E_EDGES) {
                int s = ei[e];
                int d = ei[E_EDGES + e];
                float w = ew[e];
                int b = d >> 6;
                uint2 ent;
                ent.x = (unsigned int)s |
                        ((unsigned int)__half_as_ushort(__float2half_rn(w)) << 16);
                ent.y = (unsigned int)d;
                staging[(size_t)b * BCAP + gbase[b] + lr[i]] = ent;
            }
        }
        return;
    }

    // ---------------- gemm: xp = x @ W via fp16 MFMA, a_src/a_dst ------------
    int gb = blockIdx.x - NCH;
    int r0 = gb * 32;

    // stage x-tile (32 rows x 128 k) as fp16, row stride XROW_B (272 B:
    // 16-lane b128 reads at stride 272 alias 2-way on banks = free)
    for (int i = t; i < 1024; i += 256) {
        int row = i >> 5, c4 = i & 31;
        float4 v = make_float4(0.f, 0.f, 0.f, 0.f);
        if (r0 + row < N_NODES) v = ((const float4*)x)[(size_t)(r0 + row) * 32 + c4];
        __half2 h01 = __floats2half2_rn(v.x, v.y);
        __half2 h23 = __floats2half2_rn(v.z, v.w);
        uint2 pk;
        pk.x = *(unsigned int*)&h01;
        pk.y = *(unsigned int*)&h23;
        *(uint2*)(smem + XROW_B * row + 8 * c4) = pk;
    }
    __syncthreads();

    // MFMA: wave wv computes all 32 rows x cols [32wv, 32wv+32).
    // A (LDS) and B (global WT, L2-resident) use the same k-bijection
    // (group g owns k = 32s+8g..+8), so the dot product is exact regardless
    // of the ISA's internal k order. (refcheck'd in round 5)
    int lane = t & 63;
    int wv = t >> 6;
    int g = lane >> 4, q = lane & 15;
    int cb = 32 * wv;
    f32x4_t acc2[2][2] = {};
    {
        const char* pB = (const char*)wt;
        #pragma unroll
        for (int s = 0; s < 4; s++) {
            half8 a0 = *(const half8*)(smem + XROW_B * q + 64 * s + 16 * g);
            half8 a1 = *(const half8*)(smem + XROW_B * (16 + q) + 64 * s + 16 * g);
            half8 b0 = *(const half8*)(pB + (cb + q) * 256 + 64 * s + 16 * g);
            half8 b1 = *(const half8*)(pB + (cb + 16 + q) * 256 + 64 * s + 16 * g);
            acc2[0][0] = __builtin_amdgcn_mfma_f32_16x16x32_f16(a0, b0, acc2[0][0], 0, 0, 0);
            acc2[0][1] = __builtin_amdgcn_mfma_f32_16x16x32_f16(a0, b1, acc2[0][1], 0, 0, 0);
            acc2[1][0] = __builtin_amdgcn_mfma_f32_16x16x32_f16(a1, b0, acc2[1][0], 0, 0, 0);
            acc2[1][1] = __builtin_amdgcn_mfma_f32_16x16x32_f16(a1, b1, acc2[1][1], 0, 0, 0);
        }
    }
    __syncthreads();
    // C/D mapping (HW-verified): col = lane&15, row = (lane>>4)*4 + reg.
    // sxp row stride 132 floats: C-write banks (132*row+col)%32 -> g,g+2
    // collide only (2-way = free).
    float* sxp = (float*)smem;   // [32][132] fp32, reuses x-stage region
    {
        #pragma unroll
        for (int m = 0; m < 2; m++)
            #pragma unroll
            for (int nn = 0; nn < 2; nn++)
                #pragma unroll
                for (int r = 0; r < 4; r++)
                    sxp[(m * 16 + g * 4 + r) * 132 + cb + nn * 16 + q] = acc2[m][nn][r];
    }
    __syncthreads();

    // epilogue: pack fp16 xph + a_src/a_dst (reads [32][132] padded rows)
    int tc = t & 31;   // col group: cols tc*4..tc*4+3
    int tr = t >> 5;   // row group: rows tr*4..tr*4+3
    float4 s4 = ((const float4*)att_src)[tc];
    float4 d4 = ((const float4*)att_dst)[tc];
    int h = tc >> 3;
    #pragma unroll
    for (int r = 0; r < 4; r++) {
        int row = r0 + tr * 4 + r;
        if (row < N_NODES) {
            float4 a = ((const float4*)sxp)[(tr * 4 + r) * 33 + tc];
            __half2 h01 = __floats2half2_rn(a.x, a.y);
            __half2 h23 = __floats2half2_rn(a.z, a.w);
            uint2 pk;
            pk.x = *(unsigned int*)&h01;
            pk.y = *(unsigned int*)&h23;
            ((uint2*)xph)[(size_t)row * 32 + tc] = pk;
            float ps = a.x * s4.x + a.y * s4.y + a.z * s4.z + a.w * s4.w;
            float pd = a.x * d4.x + a.y * d4.y + a.z * d4.z + a.w * d4.w;
            ps += __shfl_down(ps, 4, 8); ps += __shfl_down(ps, 2, 8); ps += __shfl_down(ps, 1, 8);
            pd += __shfl_down(pd, 4, 8); pd += __shfl_down(pd, 2, 8); pd += __shfl_down(pd, 1, 8);
            if ((tc & 7) == 0) {
                a_src[(size_t)row * 4 + h] = ps;
                a_dst[(size_t)row * 4 + h] = pd;
            }
        }
    }
}

// pass 2: bucket -> padded CSR + counts; block 0 also ew total.
__global__ __launch_bounds__(256) void k_p2(const uint2* __restrict__ staging,
                                            const int* __restrict__ bcur,
                                            const float* __restrict__ ewPart,
                                            unsigned int* __restrict__ pairs,
                                            int* __restrict__ counts, float* __restrict__ scal) {
    int b = blockIdx.x, t = threadIdx.x;
    __shared__ int cnt2[64];
    __shared__ float wr2[4];
    if (b == 0) {
        float s = 0.f;
        for (int i = t; i < NCH; i += 256) s += ewPart[i];
        #pragma unroll
        for (int off = 32; off; off >>= 1) s += __shfl_down(s, off, 64);
        if ((t & 63) == 0) wr2[t >> 6] = s;
    }
    if (t < 64) cnt2[t] = 0;
    __syncthreads();
    if (b == 0 && t == 0) scal[0] = wr2[0] + wr2[1] + wr2[2] + wr2[3];
    int tot = bcur[b];
    const uint2* sg = staging + (size_t)b * BCAP;
    for (int i = t; i < tot; i += 256) {
        uint2 ent = sg[i];
        int d = (int)ent.y;
        int r = atomicAdd(&cnt2[d & 63], 1);
        pairs[(size_t)d * PAD + r] = ent.x;
    }
    __syncthreads();
    int n = (b << 6) + t;
    if (t < 64 && n < N_NODES) counts[n] = cnt2[t];
}

// pass 3: wave-per-node aggregate, NO barriers.
// (unchanged: hoisted alpha phase staged in wave-private LDS,
// gather loop to cnt rounded up to 4.)
__global__ __launch_bounds__(256) void k_p3(const unsigned int* __restrict__ xpu,
                                            const float* __restrict__ a_src,
                                            const float* __restrict__ a_dst,
                                            const int* __restrict__ counts,
                                            const unsigned int* __restrict__ pairs,
                                            const float* __restrict__ scal,
                                            const float* __restrict__ bias,
                                            const float* __restrict__ gamma,
                                            const float* __restrict__ beta,
                                            float* __restrict__ out) {
    // [wave][head][slot]: slot stride 100 (not 96) so the 4 head-groups'
    // broadcast reads land in distinct banks (word stride 200 = 8 mod 32).
    __shared__ unsigned long long sal[4][4][100];   // 12.8 KB
    int lane = threadIdx.x & 63;
    int wv = threadIdx.x >> 6;
    int n = blockIdx.x * 4 + wv;
    if (n >= N_NODES) return;

    int h = lane >> 4;        // head for this lane's channel pair
    int em = lane & 15;       // edge slot within a 16-edge batch

    float4 K = *(const float4*)(scal + 4);
    float Kh = sel4(K, h);
    float mean_ew = scal[0] * (1.0f / E_EDGES);

    int cnt = __builtin_amdgcn_readfirstlane(counts[n]);
    float4 ad4 = *(const float4*)(a_dst + (size_t)4 * n);
    float4 as4 = *(const float4*)(a_src + (size_t)4 * n);
    float adh = sel4(ad4, h);
    float aself = exp2f(lrelu(sel4(as4, h) + adh + Kh * mean_ew) * LOG2E);

    // own row (self term), issued early to hide latency
    unsigned int pv = xpu[(size_t)n * 64 + lane];
    float2 f = __half22float2(*(__half2*)&pv);
    float acc0 = aself * f.x, acc1 = aself * f.y;

    // ---------- alpha phase: all batches up front ----------
    unsigned long long* sl = &sal[wv][h][0];
    const unsigned int* prow = pairs + (size_t)n * PAD;
    float den = 0.f;
    #pragma unroll
    for (int b = 0; b < 6; b++) {
        if (b * 16 < cnt) {                 // wave-uniform -> scalar branch
            int e = b * 16 + em;
            float alpha = 0.f;
            int s = n;
            if (e < cnt) {
                unsigned int pk = prow[e];
                s = (int)(pk & 0xFFFFu);
                float w = __half2float(__ushort_as_half((unsigned short)(pk >> 16)));
                float4 av = *(const float4*)(a_src + (size_t)4 * s);
                alpha = exp2f(lrelu(sel4(av, h) + adh + Kh * w) * LOG2E);
            }
            den += alpha;
            sl[e] = ((unsigned long long)__float_as_uint(alpha) << 32) | (unsigned int)s;
        }
    }

    // ---------- gather phase ----------
    int cnt4 = (cnt + 3) & ~3;
    for (int e = 0; e < cnt4; e += 4) {
        ulonglong2 p01 = *(const ulonglong2*)(sl + e);
        ulonglong2 p23 = *(const ulonglong2*)(sl + e + 2);
        unsigned long long pq[4] = {p01.x, p01.y, p23.x, p23.y};
        #pragma unroll
        for (int q = 0; q < 4; q++) {
            unsigned int sj = (unsigned int)pq[q];
            float aj = __uint_as_float((unsigned int)(pq[q] >> 32));
            unsigned int g = xpu[(size_t)sj * 64 + lane];
            __half2 hh = *(__half2*)&g;
            acc0 = fmaf(aj, __half2float(__low2half(hh)), acc0);
            acc1 = fmaf(aj, __half2float(__high2half(hh)), acc1);
        }
    }

    // reduce den across the 16 lanes sharing this head
    den += __shfl_xor(den, 1, 64);
    den += __shfl_xor(den, 2, 64);
    den += __shfl_xor(den, 4, 64);
    den += __shfl_xor(den, 8, 64);
    den += aself;

    float inv = 1.0f / (den + 1e-16f);
    float2 b2 = ((const float2*)bias)[lane];
    float y0 = fmaf(acc0, inv, b2.x);
    float y1 = fmaf(acc1, inv, b2.y);

    // LayerNorm over 128 channels (2 per lane) via full-wave xor reduce
    float s1 = y0 + y1;
    #pragma unroll
    for (int off = 1; off < 64; off <<= 1) s1 += __shfl_xor(s1, off, 64);
    float mu = s1 * (1.f / 128.f);
    float d0 = y0 - mu, d1 = y1 - mu;
    float s2 = d0 * d0 + d1 * d1;
    #pragma unroll
    for (int off = 1; off < 64; off <<= 1) s2 += __shfl_xor(s2, off, 64);
    float rstd = rsqrtf(s2 * (1.f / 128.f) + LN_EPS);
    float2 g2 = ((const float2*)gamma)[lane];
    float2 be2 = ((const float2*)beta)[lane];
    float o0 = fmaf(d0 * rstd, g2.x, be2.x);
    float o1 = fmaf(d1 * rstd, g2.y, be2.y);
    o0 = o0 > 0.f ? o0 : expm1f(o0);
    o1 = o1 > 0.f ? o1 : expm1f(o1);
    float2 o; o.x = o0; o.y = o1;
    ((float2*)out)[(size_t)n * 64 + lane] = o;
}

extern "C" void kernel_launch(void* const* d_in, const int* in_sizes, int n_in,
                              void* d_out, int out_size, void* d_ws, size_t ws_size,
                              hipStream_t stream) {
    const float* x        = (const float*)d_in[0];
    const int*   ei       = (const int*)d_in[1];
    const float* ew       = (const float*)d_in[2];
    const float* W        = (const float*)d_in[3];
    const float* att_src  = (const float*)d_in[4];
    const float* att_dst  = (const float*)d_in[5];
    const float* W_edge   = (const float*)d_in[6];
    const float* att_edge = (const float*)d_in[7];
    const float* bias     = (const float*)d_in[8];
    const float* gamma    = (const float*)d_in[9];
    const float* beta     = (const float*)d_in[10];
    float* out = (float*)d_out;

    char* ws = (char*)d_ws;
    float* scal      = (float*)(ws + OFF_SCAL);
    int*   bcur      = (int*)(ws + OFF_BCUR);
    float* ewPart    = (float*)(ws + OFF_EWPART);
    int*   counts    = (int*)(ws + OFF_COUNTS);
    float* a_src     = (float*)(ws + OFF_ASRC);
    float* a_dst     = (float*)(ws + OFF_ADST);
    unsigned short* xph = (unsigned short*)(ws + OFF_XPH);
    unsigned int* pairs = (unsigned int*)(ws + OFF_PAIRS);
    uint2* staging   = (uint2*)(ws + OFF_STAGE);
    unsigned short* wt  = (unsigned short*)(ws + OFF_WT);

    hipMemsetAsync(bcur, 0, NBK * sizeof(int), stream);
    k_w<<<1, TPB, 0, stream>>>(W, W_edge, att_edge, wt, scal);
    k_A<<<NCH + NGB, TPB, 0, stream>>>(x, wt, att_src, att_dst, ei, ew,
                                       xph, a_src, a_dst, scal, bcur, staging, ewPart);
    k_p2<<<NBK, TPB, 0, stream>>>(staging, bcur, ewPart, pairs, counts, scal);
    k_p3<<<12500, TPB, 0, stream>>>((const unsigned int*)xph, a_src, a_dst, counts, pairs, scal,
                                    bias, gamma, beta, out);
}

// Round 7
// 222.180 us; speedup vs baseline: 1.0637x; 1.0637x over previous
//
#include <hip/hip_runtime.h>
#include <hip/hip_fp16.h>
#include <cstddef>

#define N_NODES 50000
#define E_EDGES 1600000
#define NEG_SLOPE 0.2f
#define LN_EPS 1e-5f
#define LOG2E 1.4426950408889634f
#define PAD 96        // max in-degree; Poisson(32) -> P(deg>96) ~ 1e-19

#define NBK 3125      // dst buckets of 16 nodes: 50000/16 exactly
#define BCAP 704      // entries per bucket (mean 512, +8.5 sigma headroom)
#define PCH 4096      // edges per partition chunk
#define NCH 391       // ceil(E/PCH)
#define NGB 1563      // gemm blocks: ceil(N/32)
#define TPB 256

// ---------------- workspace layout (bytes) ----------------
// scal[0] = ew_sum (atomic), scal[4..7] = K[h]
#define OFF_SCAL    0u
#define OFF_BCUR    256u                       // NBK ints -> ends 12,756+256
#define OFF_ASRC    208256u                    // N*4 floats -> 1,008,256
#define OFF_ADST    1008256u                   // N*4 floats -> 1,808,256
#define OFF_XPH     1808256u                   // N*128 halfs -> 14,608,256
#define OFF_STAGE   14608256u                  // NBK*BCAP uint2 = 17.6MB -> 32,208,256
#define OFF_WT      32208256u                  // 128x128 fp16 W^T -> 32,241,024

// LDS geometry for the MFMA gemm branch
#define XROW_B   272        // x-stage: 136 halves per row (128 + 8 pad); 32 rows = 8704 B
// sxp C-roundtrip: [32][132] fp32 = 16896 B; p1 branch needs 2*NBK ints = 25016 B

typedef _Float16 half8 __attribute__((ext_vector_type(8)));
typedef float f32x4_t __attribute__((ext_vector_type(4)));

__device__ __forceinline__ float lrelu(float x) { return x > 0.f ? x : NEG_SLOPE * x; }

__device__ __forceinline__ float sel4(float4 v, int h) {
    float ab = (h & 1) ? v.y : v.x;
    float cd = (h & 1) ? v.w : v.z;
    return (h & 2) ? cd : ab;
}

// prologue (64 blocks): W^T fp16, K[h] reduce, zero bcur + scal[0].
__global__ __launch_bounds__(256) void k_w(const float* __restrict__ W,
                                           const float* __restrict__ W_edge,
                                           const float* __restrict__ att_edge,
                                           unsigned short* __restrict__ wt,
                                           float* __restrict__ scal,
                                           int* __restrict__ bcur) {
    int t = threadIdx.x;
    int gid = blockIdx.x * 256 + t;
    if (blockIdx.x == 0) {
        if (t < 128) {
            float p = W_edge[t] * att_edge[t];
            #pragma unroll
            for (int off = 16; off; off >>= 1) p += __shfl_down(p, off, 32);
            if ((t & 31) == 0) scal[4 + (t >> 5)] = p;
        }
        if (t == 128) scal[0] = 0.f;
    }
    if (gid < NBK) bcur[gid] = 0;
    if (gid < 16384) {
        int k = gid >> 7, c = gid & 127;
        wt[c * 128 + k] = __half_as_ushort(__float2half_rn(W[gid]));
    }
}

// fused independent work: blocks [0,NCH) = edge partition (p1, 16-node
// buckets); blocks [NCH, NCH+NGB) = node GEMM (MFMA fp16, B direct from
// global WT). bcur/scal pre-zeroed by k_w.
__global__ __launch_bounds__(256, 4) void k_A(const float* __restrict__ x,
                                              const unsigned short* __restrict__ wt,
                                              const float* __restrict__ att_src, const float* __restrict__ att_dst,
                                              const int* __restrict__ ei, const float* __restrict__ ew,
                                              unsigned short* __restrict__ xph, float* __restrict__ a_src,
                                              float* __restrict__ a_dst, float* __restrict__ scal,
                                              int* __restrict__ bcur, uint2* __restrict__ staging) {
    __shared__ __align__(16) char smem[25088];
    int t = threadIdx.x;

    if (blockIdx.x < NCH) {
        // ---------------- p1: partition edges into 16-node dst buckets ------
        int* cnt   = (int*)smem;        // NBK ints
        int* gbase = cnt + NBK;         // NBK ints
        for (int i = t; i < NBK; i += 256) cnt[i] = 0;
        __syncthreads();

        int e0 = blockIdx.x * PCH;
        int lr[16];
        float s_ew = 0.f;
        #pragma unroll
        for (int i = 0; i < 16; i++) {
            int e = e0 + i * 256 + t;
            lr[i] = 0;
            if (e < E_EDGES) {
                int d = ei[E_EDGES + e];
                s_ew += ew[e];
                lr[i] = atomicAdd(&cnt[d >> 4], 1);
            }
        }
        #pragma unroll
        for (int off = 32; off; off >>= 1) s_ew += __shfl_down(s_ew, off, 64);
        __syncthreads();            // cnt final before gbase pass
        if ((t & 63) == 0) atomicAdd(scal, s_ew);
        for (int i = t; i < NBK; i += 256) gbase[i] = atomicAdd(&bcur[i], cnt[i]);
        __syncthreads();

        #pragma unroll
        for (int i = 0; i < 16; i++) {
            int e = e0 + i * 256 + t;
            if (e < E_EDGES) {
                int s = ei[e];
                int d = ei[E_EDGES + e];
                float w = ew[e];
                int b = d >> 4;
                uint2 ent;
                ent.x = (unsigned int)s |
                        ((unsigned int)__half_as_ushort(__float2half_rn(w)) << 16);
                ent.y = (unsigned int)d;
                staging[(size_t)b * BCAP + gbase[b] + lr[i]] = ent;
            }
        }
        return;
    }

    // ---------------- gemm: xp = x @ W via fp16 MFMA, a_src/a_dst ------------
    int gb = blockIdx.x - NCH;
    int r0 = gb * 32;

    for (int i = t; i < 1024; i += 256) {
        int row = i >> 5, c4 = i & 31;
        float4 v = make_float4(0.f, 0.f, 0.f, 0.f);
        if (r0 + row < N_NODES) v = ((const float4*)x)[(size_t)(r0 + row) * 32 + c4];
        __half2 h01 = __floats2half2_rn(v.x, v.y);
        __half2 h23 = __floats2half2_rn(v.z, v.w);
        uint2 pk;
        pk.x = *(unsigned int*)&h01;
        pk.y = *(unsigned int*)&h23;
        *(uint2*)(smem + XROW_B * row + 8 * c4) = pk;
    }
    __syncthreads();

    // A (LDS) and B (global WT, L2-resident) use the same k-bijection
    // (group g owns k = 32s+8g..+8) -> dot product exact. (refcheck'd r5/r6)
    int lane = t & 63;
    int wv = t >> 6;
    int g = lane >> 4, q = lane & 15;
    int cb = 32 * wv;
    f32x4_t acc2[2][2] = {};
    {
        const char* pB = (const char*)wt;
        #pragma unroll
        for (int s = 0; s < 4; s++) {
            half8 a0 = *(const half8*)(smem + XROW_B * q + 64 * s + 16 * g);
            half8 a1 = *(const half8*)(smem + XROW_B * (16 + q) + 64 * s + 16 * g);
            half8 b0 = *(const half8*)(pB + (cb + q) * 256 + 64 * s + 16 * g);
            half8 b1 = *(const half8*)(pB + (cb + 16 + q) * 256 + 64 * s + 16 * g);
            acc2[0][0] = __builtin_amdgcn_mfma_f32_16x16x32_f16(a0, b0, acc2[0][0], 0, 0, 0);
            acc2[0][1] = __builtin_amdgcn_mfma_f32_16x16x32_f16(a0, b1, acc2[0][1], 0, 0, 0);
            acc2[1][0] = __builtin_amdgcn_mfma_f32_16x16x32_f16(a1, b0, acc2[1][0], 0, 0, 0);
            acc2[1][1] = __builtin_amdgcn_mfma_f32_16x16x32_f16(a1, b1, acc2[1][1], 0, 0, 0);
        }
    }
    __syncthreads();
    // C/D mapping (HW-verified): col = lane&15, row = (lane>>4)*4 + reg.
    float* sxp = (float*)smem;   // [32][132] fp32
    {
        #pragma unroll
        for (int m = 0; m < 2; m++)
            #pragma unroll
            for (int nn = 0; nn < 2; nn++)
                #pragma unroll
                for (int r = 0; r < 4; r++)
                    sxp[(m * 16 + g * 4 + r) * 132 + cb + nn * 16 + q] = acc2[m][nn][r];
    }
    __syncthreads();

    int tc = t & 31;
    int tr = t >> 5;
    float4 s4 = ((const float4*)att_src)[tc];
    float4 d4 = ((const float4*)att_dst)[tc];
    int h = tc >> 3;
    #pragma unroll
    for (int r = 0; r < 4; r++) {
        int row = r0 + tr * 4 + r;
        if (row < N_NODES) {
            float4 a = ((const float4*)sxp)[(tr * 4 + r) * 33 + tc];
            __half2 h01 = __floats2half2_rn(a.x, a.y);
            __half2 h23 = __floats2half2_rn(a.z, a.w);
            uint2 pk;
            pk.x = *(unsigned int*)&h01;
            pk.y = *(unsigned int*)&h23;
            ((uint2*)xph)[(size_t)row * 32 + tc] = pk;
            float ps = a.x * s4.x + a.y * s4.y + a.z * s4.z + a.w * s4.w;
            float pd = a.x * d4.x + a.y * d4.y + a.z * d4.z + a.w * d4.w;
            ps += __shfl_down(ps, 4, 8); ps += __shfl_down(ps, 2, 8); ps += __shfl_down(ps, 1, 8);
            pd += __shfl_down(pd, 4, 8); pd += __shfl_down(pd, 2, 8); pd += __shfl_down(pd, 1, 8);
            if ((tc & 7) == 0) {
                a_src[(size_t)row * 4 + h] = ps;
                a_dst[(size_t)row * 4 + h] = pd;
            }
        }
    }
}

// pass 3 (fused with old k_p2): one block per 16-node bucket.
// Phase A: coalesced read of this bucket's staging, LDS-scatter into per-node
// pairs lists (LDS atomics). Phase B: 4 waves x 4 nodes, the proven per-node
// pipeline (alpha phase staged in wave-private LDS; gather to cnt4).
// Eliminates: k_p2 dispatch, global pairs/counts arrays, memset.
__global__ __launch_bounds__(256) void k_p3(const unsigned int* __restrict__ xpu,
                                            const float* __restrict__ a_src,
                                            const float* __restrict__ a_dst,
                                            const uint2* __restrict__ staging,
                                            const int* __restrict__ bcur,
                                            const float* __restrict__ scal,
                                            const float* __restrict__ bias,
                                            const float* __restrict__ gamma,
                                            const float* __restrict__ beta,
                                            float* __restrict__ out) {
    __shared__ unsigned int pl[16][100];            // 6.4 KB pairs (16 nodes x PAD<=96)
    __shared__ int lcnt[16];
    __shared__ unsigned long long sal[4][4][100];   // 12.8 KB alpha stage (per wave)
    int b = blockIdx.x;
    int t = threadIdx.x;

    // ---------- phase A: bucket -> LDS pairs ----------
    if (t < 16) lcnt[t] = 0;
    __syncthreads();
    int tot = bcur[b];
    const uint2* sg = staging + (size_t)b * BCAP;
    for (int i = t; i < tot; i += 256) {
        uint2 ent = sg[i];
        int dl = (int)ent.y & 15;
        int r = atomicAdd(&lcnt[dl], 1);
        pl[dl][r] = ent.x;
    }
    __syncthreads();

    // ---------- phase B: 4 waves x 4 nodes ----------
    int lane = t & 63;
    int wv = t >> 6;
    int h = lane >> 4;        // head for this lane's channel pair
    int em = lane & 15;       // edge slot within a 16-edge batch

    float4 K = *(const float4*)(scal + 4);
    float Kh = sel4(K, h);
    float mean_ew = scal[0] * (1.0f / E_EDGES);
    unsigned long long* sl = &sal[wv][h][0];

    for (int j = 0; j < 4; j++) {
        int nl = (wv << 2) + j;
        int n = (b << 4) + nl;             // N = 3125*16 exactly, no tail
        int cnt = __builtin_amdgcn_readfirstlane(lcnt[nl]);

        float4 ad4 = *(const float4*)(a_dst + (size_t)4 * n);
        float4 as4 = *(const float4*)(a_src + (size_t)4 * n);
        float adh = sel4(ad4, h);
        float aself = exp2f(lrelu(sel4(as4, h) + adh + Kh * mean_ew) * LOG2E);

        unsigned int pv = xpu[(size_t)n * 64 + lane];
        float2 f = __half22float2(*(__half2*)&pv);
        float acc0 = aself * f.x, acc1 = aself * f.y;

        // alpha phase: all batches up front (pairs from LDS)
        float den = 0.f;
        #pragma unroll
        for (int bb = 0; bb < 6; bb++) {
            if (bb * 16 < cnt) {               // wave-uniform branch
                int e = bb * 16 + em;
                float alpha = 0.f;
                int s = n;
                if (e < cnt) {
                    unsigned int pk = pl[nl][e];
                    s = (int)(pk & 0xFFFFu);
                    float w = __half2float(__ushort_as_half((unsigned short)(pk >> 16)));
                    float4 av = *(const float4*)(a_src + (size_t)4 * s);
                    alpha = exp2f(lrelu(sel4(av, h) + adh + Kh * w) * LOG2E);
                }
                den += alpha;
                sl[e] = ((unsigned long long)__float_as_uint(alpha) << 32) | (unsigned int)s;
            }
        }

        // gather phase
        int cnt4 = (cnt + 3) & ~3;
        for (int e = 0; e < cnt4; e += 4) {
            ulonglong2 p01 = *(const ulonglong2*)(sl + e);
            ulonglong2 p23 = *(const ulonglong2*)(sl + e + 2);
            unsigned long long pq[4] = {p01.x, p01.y, p23.x, p23.y};
            #pragma unroll
            for (int q = 0; q < 4; q++) {
                unsigned int sj = (unsigned int)pq[q];
                float aj = __uint_as_float((unsigned int)(pq[q] >> 32));
                unsigned int g = xpu[(size_t)sj * 64 + lane];
                __half2 hh = *(__half2*)&g;
                acc0 = fmaf(aj, __half2float(__low2half(hh)), acc0);
                acc1 = fmaf(aj, __half2float(__high2half(hh)), acc1);
            }
        }

        den += __shfl_xor(den, 1, 64);
        den += __shfl_xor(den, 2, 64);
        den += __shfl_xor(den, 4, 64);
        den += __shfl_xor(den, 8, 64);
        den += aself;

        float inv = 1.0f / (den + 1e-16f);
        float2 b2 = ((const float2*)bias)[lane];
        float y0 = fmaf(acc0, inv, b2.x);
        float y1 = fmaf(acc1, inv, b2.y);

        float s1 = y0 + y1;
        #pragma unroll
        for (int off = 1; off < 64; off <<= 1) s1 += __shfl_xor(s1, off, 64);
        float mu = s1 * (1.f / 128.f);
        float d0 = y0 - mu, d1 = y1 - mu;
        float s2 = d0 * d0 + d1 * d1;
        #pragma unroll
        for (int off = 1; off < 64; off <<= 1) s2 += __shfl_xor(s2, off, 64);
        float rstd = rsqrtf(s2 * (1.f / 128.f) + LN_EPS);
        float2 g2 = ((const float2*)gamma)[lane];
        float2 be2 = ((const float2*)beta)[lane];
        float o0 = fmaf(d0 * rstd, g2.x, be2.x);
        float o1 = fmaf(d1 * rstd, g2.y, be2.y);
        o0 = o0 > 0.f ? o0 : expm1f(o0);
        o1 = o1 > 0.f ? o1 : expm1f(o1);
        float2 o; o.x = o0; o.y = o1;
        ((float2*)out)[(size_t)n * 64 + lane] = o;
    }
}

extern "C" void kernel_launch(void* const* d_in, const int* in_sizes, int n_in,
                              void* d_out, int out_size, void* d_ws, size_t ws_size,
                              hipStream_t stream) {
    const float* x        = (const float*)d_in[0];
    const int*   ei       = (const int*)d_in[1];
    const float* ew       = (const float*)d_in[2];
    const float* W        = (const float*)d_in[3];
    const float* att_src  = (const float*)d_in[4];
    const float* att_dst  = (const float*)d_in[5];
    const float* W_edge   = (const float*)d_in[6];
    const float* att_edge = (const float*)d_in[7];
    const float* bias     = (const float*)d_in[8];
    const float* gamma    = (const float*)d_in[9];
    const float* beta     = (const float*)d_in[10];
    float* out = (float*)d_out;

    char* ws = (char*)d_ws;
    float* scal      = (float*)(ws + OFF_SCAL);
    int*   bcur      = (int*)(ws + OFF_BCUR);
    float* a_src     = (float*)(ws + OFF_ASRC);
    float* a_dst     = (float*)(ws + OFF_ADST);
    unsigned short* xph = (unsigned short*)(ws + OFF_XPH);
    uint2* staging   = (uint2*)(ws + OFF_STAGE);
    unsigned short* wt  = (unsigned short*)(ws + OFF_WT);

    k_w<<<64, TPB, 0, stream>>>(W, W_edge, att_edge, wt, scal, bcur);
    k_A<<<NCH + NGB, TPB, 0, stream>>>(x, wt, att_src, att_dst, ei, ew,
                                       xph, a_src, a_dst, scal, bcur, staging);
    k_p3<<<NBK, TPB, 0, stream>>>((const unsigned int*)xph, a_src, a_dst, staging, bcur, scal,
                                  bias, gamma, beta, out);
}